// Round 26
// baseline (110.833 us; speedup 1.0000x reference)
//
#include <hip/hip_runtime.h>
#include <hip/hip_bf16.h>

#define S_LEN 1024
#define DH 64
#define QB 128     // q rows per workgroup (doubled: amortizes staging/barriers)
#define NQB 8      // S_LEN / QB
#define KT 64      // k rows per tile
#define NKT 16     // S_LEN / KT
#define LDP 72     // padded LDS row length (bf16 elems); 144B stride
#define NTHREADS 512

typedef __attribute__((ext_vector_type(8))) short bf16x8;
typedef __attribute__((ext_vector_type(4))) float f32x4;
typedef unsigned long long u64;

__device__ __forceinline__ unsigned short f2bf(float f) {
  unsigned u = __float_as_uint(f);
  u = u + 0x7FFFu + ((u >> 16) & 1u);   // RNE
  return (unsigned short)(u >> 16);
}
__device__ __forceinline__ float bf2f(unsigned short s) {
  return __uint_as_float((unsigned)s << 16);
}
__device__ __forceinline__ unsigned pk2(float a, float b) {
  __hip_bfloat162 h = __float22bfloat162_rn(float2{a, b});
  return *reinterpret_cast<unsigned*>(&h);
}

// ---- pre-pass: pack int32 mask -> 1 bit/elem ----
__global__ __launch_bounds__(256)
void maskpack_kernel(const int* __restrict__ mask, u64* __restrict__ bits) {
  int w    = blockIdx.x * 4 + (threadIdx.x >> 6);
  int lane = threadIdx.x & 63;
  int m = mask[(size_t)w * 64 + lane];
  u64 word = __ballot(m != 0);
  if (lane == 0) bits[w] = word;
}

__global__ __launch_bounds__(NTHREADS, 2)
void sdpa_kernel(const float* __restrict__ qg, const float* __restrict__ kg,
                 const float* __restrict__ vg, const u64* __restrict__ bitsg,
                 float* __restrict__ outg, float* __restrict__ attng)
{
  // LDS: Qs (prologue) aliases Ps (pass 2) — both 128x72 / 8x16x72 = 18.4 KB.
  // Ks + Vt 9.2 KB each; total 37.3 KB -> 4 blocks/CU capacity (grid needs 2).
  // Pass 1 ping-pongs K between Ks and (pass-1-idle) Vt: 1 barrier/tile.
  __shared__ unsigned short QsPs[QB][LDP];
  __shared__ unsigned short Ks[KT][LDP];
  __shared__ unsigned short Vt[DH][LDP];      // pass1: K pong buffer / pass2: V^T [d][k]
  __shared__ float invLds[QB];

  unsigned short (*Qs)[LDP] = QsPs;
  unsigned short (*Ps)[16][LDP] = (unsigned short (*)[16][LDP])QsPs;

  const int tid  = threadIdx.x;
  const int wid  = tid >> 6;                  // 0..7
  const int lane = tid & 63;
  const int lrow = lane & 15;
  const int lhi  = lane >> 4;

  // XCD swizzle (validated round 21): each XCD owns 64 consecutive logical
  // blocks = 8 complete bh groups (8 qbi each). 512 % 8 == 0 -> bijective.
  const int P = blockIdx.x;
  const int L = (P & 7) * 64 + (P >> 3);
  const int qbi = L & (NQB - 1);
  const int bh  = L >> 3;
  const int b   = bh >> 4;

  const size_t qkv_off = (size_t)bh * (S_LEN * DH);
  const float* qb_ptr = qg + qkv_off + (size_t)qbi * QB * DH;
  const float* kb_ptr = kg + qkv_off;
  const float* vb_ptr = vg + qkv_off;
  const int q0 = qbi * QB;
  const int qrow_l = wid * 16 + lhi * 4;      // 0..127

  const u64* bptr = bitsg + ((size_t)(b * S_LEN + q0 + qrow_l)) * NKT;  // + r*NKT + kt
  float* attn_base = attng + (size_t)bh * (S_LEN * S_LEN);

  // ---- prologue: issue tile-0 K + bits loads ----
  float4 Kp[2];
  u64 Bc[4], Bn[4];
  #pragma unroll
  for (int i = 0; i < 2; ++i) {
    int idx = tid + NTHREADS * i;
    Kp[i] = *(const float4*)(kb_ptr + (size_t)(idx >> 4) * DH + ((idx & 15) << 2));
  }
  #pragma unroll
  for (int r = 0; r < 4; ++r) Bc[r] = bptr[r * NKT + 0];

  // ---- stage Q (128x64 f32 -> bf16): 2048 float4 over 512 threads ----
  #pragma unroll
  for (int i = 0; i < 4; ++i) {
    int idx = tid + NTHREADS * i;
    int row = idx >> 4, c4 = (idx & 15) << 2;
    float4 t = *(const float4*)(qb_ptr + row * DH + c4);
    uint2 w; w.x = pk2(t.x, t.y); w.y = pk2(t.z, t.w);
    *(uint2*)&Qs[row][c4] = w;
  }
  __syncthreads();
  const bf16x8 qf0 = *(const bf16x8*)&Qs[wid * 16 + lrow][lhi * 8];
  const bf16x8 qf1 = *(const bf16x8*)&Qs[wid * 16 + lrow][32 + lhi * 8];

  // stage K tile 0 into Ks; issue tile-1 loads
  #pragma unroll
  for (int i = 0; i < 2; ++i) {
    int idx = tid + NTHREADS * i;
    int row = idx >> 4, c4 = (idx & 15) << 2;
    float4 t = Kp[i];
    uint2 w; w.x = pk2(t.x, t.y); w.y = pk2(t.z, t.w);
    *(uint2*)&Ks[row][c4] = w;
  }
  #pragma unroll
  for (int i = 0; i < 2; ++i) {
    int idx = tid + NTHREADS * i;
    Kp[i] = *(const float4*)(kb_ptr + (size_t)KT * DH + (size_t)(idx >> 4) * DH + ((idx & 15) << 2));
  }

  // ================= pass 1: rowsums, K ping-pong, 1 barrier/tile =================
  float rs[4] = {0.f, 0.f, 0.f, 0.f};

  for (int kt = 0; kt < NKT; ++kt) {
    __syncthreads();   // tile kt staged & visible; reads of kt-1's buffer done

    unsigned short (*cur)[LDP] = (kt & 1) ? Vt : Ks;
    unsigned short (*nxt)[LDP] = (kt & 1) ? Ks : Vt;

    if (kt + 1 < NKT) {
      #pragma unroll
      for (int i = 0; i < 2; ++i) {
        int idx = tid + NTHREADS * i;
        int row = idx >> 4, c4 = (idx & 15) << 2;
        float4 t = Kp[i];
        uint2 w; w.x = pk2(t.x, t.y); w.y = pk2(t.z, t.w);
        *(uint2*)&nxt[row][c4] = w;
      }
      if (kt + 2 < NKT) {
        const float* kn = kb_ptr + (size_t)(kt + 2) * KT * DH;
        #pragma unroll
        for (int i = 0; i < 2; ++i) {
          int idx = tid + NTHREADS * i;
          Kp[i] = *(const float4*)(kn + (size_t)(idx >> 4) * DH + ((idx & 15) << 2));
        }
      }
      #pragma unroll
      for (int r = 0; r < 4; ++r) Bn[r] = bptr[r * NKT + kt + 1];
    }

    #pragma unroll
    for (int nt = 0; nt < 4; ++nt) {
      bf16x8 kf0 = *(const bf16x8*)&cur[nt * 16 + lrow][lhi * 8];
      bf16x8 kf1 = *(const bf16x8*)&cur[nt * 16 + lrow][32 + lhi * 8];
      f32x4 acc = {0.f, 0.f, 0.f, 0.f};
      acc = __builtin_amdgcn_mfma_f32_16x16x32_bf16(qf0, kf0, acc, 0, 0, 0);
      acc = __builtin_amdgcn_mfma_f32_16x16x32_bf16(qf1, kf1, acc, 0, 0, 0);
      #pragma unroll
      for (int r = 0; r < 4; ++r) {
        bool ok = ((Bc[r] >> (nt * 16 + lrow)) & 1ull) != 0;
        float p = ok ? __expf(acc[r] * 0.125f) : 0.f;
        rs[r] += p;
      }
    }
    if (kt + 1 < NKT) {
      #pragma unroll
      for (int r = 0; r < 4; ++r) Bc[r] = Bn[r];
    }
  }

  // ---- rowsum reduce across the 16 lanes sharing each q-row ----
  #pragma unroll
  for (int r = 0; r < 4; ++r) {
    float v = rs[r];
    v += __shfl_xor(v, 1);
    v += __shfl_xor(v, 2);
    v += __shfl_xor(v, 4);
    v += __shfl_xor(v, 8);
    rs[r] = v;
  }
  float inv[4];
  #pragma unroll
  for (int r = 0; r < 4; ++r) inv[r] = 1.0f / rs[r];
  if (lrow == 0) {
    #pragma unroll
    for (int r = 0; r < 4; ++r) invLds[qrow_l + r] = inv[r];
  }

  // ---- prefetch pass-2 tile 0 (K, V, bits); latency hides under the reduce ----
  float4 Vp[2];
  #pragma unroll
  for (int i = 0; i < 2; ++i) {
    int idx = tid + NTHREADS * i;
    Kp[i] = *(const float4*)(kb_ptr + (size_t)(idx >> 4) * DH + ((idx & 15) << 2));
    Vp[i] = *(const float4*)(vb_ptr + (size_t)(idx & 63) * DH + ((idx >> 6) << 2));
  }
  #pragma unroll
  for (int r = 0; r < 4; ++r) Bc[r] = bptr[r * NKT + 0];

  f32x4 oacc[4];
  #pragma unroll
  for (int dt = 0; dt < 4; ++dt) oacc[dt] = (f32x4){0.f, 0.f, 0.f, 0.f};

  // ================= pass 2: recompute, write normalized attn, PV =================
  for (int kt = 0; kt < NKT; ++kt) {
    __syncthreads();   // prior tile's consumers of Ks/Vt/Ps done (kt=0: publishes invLds,
                       // and all pass-1 reads of Ks/Vt complete)

    #pragma unroll
    for (int i = 0; i < 2; ++i) {
      int idx = tid + NTHREADS * i;
      int row = idx >> 4, c4 = (idx & 15) << 2;
      float4 t = Kp[i];
      uint2 w; w.x = pk2(t.x, t.y); w.y = pk2(t.z, t.w);
      *(uint2*)&Ks[row][c4] = w;
    }
    #pragma unroll
    for (int i = 0; i < 2; ++i) {
      int idx = tid + NTHREADS * i;
      int row = idx & 63, c4 = (idx >> 6) << 2;
      float4 t = Vp[i];
      Vt[c4 + 0][row] = f2bf(t.x);
      Vt[c4 + 1][row] = f2bf(t.y);
      Vt[c4 + 2][row] = f2bf(t.z);
      Vt[c4 + 3][row] = f2bf(t.w);
    }
    if (kt + 1 < NKT) {
      const float* kn = kb_ptr + (size_t)(kt + 1) * KT * DH;
      const float* vn = vb_ptr + (size_t)(kt + 1) * KT * DH;
      #pragma unroll
      for (int i = 0; i < 2; ++i) {
        int idx = tid + NTHREADS * i;
        Kp[i] = *(const float4*)(kn + (size_t)(idx >> 4) * DH + ((idx & 15) << 2));
        Vp[i] = *(const float4*)(vn + (size_t)(idx & 63) * DH + ((idx >> 6) << 2));
      }
      #pragma unroll
      for (int r = 0; r < 4; ++r) Bn[r] = bptr[r * NKT + kt + 1];
    }
    __syncthreads();

    // QK^T + masked exp -> per-wave bf16 P tile
    #pragma unroll
    for (int nt = 0; nt < 4; ++nt) {
      bf16x8 kf0 = *(const bf16x8*)&Ks[nt * 16 + lrow][lhi * 8];
      bf16x8 kf1 = *(const bf16x8*)&Ks[nt * 16 + lrow][32 + lhi * 8];
      f32x4 acc = {0.f, 0.f, 0.f, 0.f};
      acc = __builtin_amdgcn_mfma_f32_16x16x32_bf16(qf0, kf0, acc, 0, 0, 0);
      acc = __builtin_amdgcn_mfma_f32_16x16x32_bf16(qf1, kf1, acc, 0, 0, 0);
      #pragma unroll
      for (int r = 0; r < 4; ++r) {
        bool ok = ((Bc[r] >> (nt * 16 + lrow)) & 1ull) != 0;
        float p = ok ? __expf(acc[r] * 0.125f) : 0.f;
        Ps[wid][lhi * 4 + r][nt * 16 + lrow] = f2bf(p);
      }
    }

    // pin compiler ordering: all Ps writes issue before cross-lane fragment reads
    asm volatile("" ::: "memory");

    // PV (per-wave Ps; same-wave in-order DS pipe; Vt protected by loop barriers)
    bf16x8 pf0 = *(const bf16x8*)&Ps[wid][lrow][lhi * 8];
    bf16x8 pf1 = *(const bf16x8*)&Ps[wid][lrow][32 + lhi * 8];
    #pragma unroll
    for (int dt = 0; dt < 4; ++dt) {
      bf16x8 vf0 = *(const bf16x8*)&Vt[dt * 16 + lrow][lhi * 8];
      bf16x8 vf1 = *(const bf16x8*)&Vt[dt * 16 + lrow][32 + lhi * 8];
      oacc[dt] = __builtin_amdgcn_mfma_f32_16x16x32_bf16(pf0, vf0, oacc[dt], 0, 0, 0);
      oacc[dt] = __builtin_amdgcn_mfma_f32_16x16x32_bf16(pf1, vf1, oacc[dt], 0, 0, 0);
    }

    // normalized attn store: NON-TEMPORAL f32x4 rows (each wave: its 16 rows x 64 cols)
    {
      float* ab = attn_base + (size_t)(q0 + wid * 16) * S_LEN + kt * KT;
      #pragma unroll
      for (int j = 0; j < 4; ++j) {
        int flat = lane + 64 * j;
        int rowl = flat >> 4;
        int c4   = (flat & 15) << 2;
        float iv = invLds[wid * 16 + rowl];
        const unsigned short* pr = &Ps[wid][rowl][c4];
        f32x4 st;
        st[0] = bf2f(pr[0]) * iv;
        st[1] = bf2f(pr[1]) * iv;
        st[2] = bf2f(pr[2]) * iv;
        st[3] = bf2f(pr[3]) * iv;
        __builtin_nontemporal_store(st, (f32x4*)(ab + (size_t)rowl * S_LEN + c4));
      }
    }

    if (kt + 1 < NKT) {
      #pragma unroll
      for (int r = 0; r < 4; ++r) Bc[r] = Bn[r];
    }
  }

  // ---- out epilogue (non-temporal: write-once stream) ----
  #pragma unroll
  for (int dt = 0; dt < 4; ++dt)
    #pragma unroll
    for (int r = 0; r < 4; ++r)
      __builtin_nontemporal_store(oacc[dt][r] * inv[r],
          outg + qkv_off + (size_t)(q0 + qrow_l + r) * DH + dt * 16 + lrow);
}

extern "C" void kernel_launch(void* const* d_in, const int* in_sizes, int n_in,
                              void* d_out, int out_size, void* d_ws, size_t ws_size,
                              hipStream_t stream) {
  const float* q    = (const float*)d_in[0];
  const float* k    = (const float*)d_in[1];
  const float* v    = (const float*)d_in[2];
  const int*   mask = (const int*)d_in[3];
  float* out  = (float*)d_out;
  float* attn = out + (size_t)4 * 16 * 1024 * 64;

  const size_t nwords = (size_t)4 * S_LEN * NKT;    // 65536 u64 = 512 KB
  u64* bits = (u64*)d_ws;                            // ws_size >= 512 KB (verified)
  maskpack_kernel<<<dim3(nwords / 4), dim3(256), 0, stream>>>(mask, bits);
  sdpa_kernel<<<dim3(64 * NQB), dim3(NTHREADS), 0, stream>>>(q, k, v, bits, out, attn);
}

// Round 28
// 108.699 us; speedup vs baseline: 1.0196x; 1.0196x over previous
//
#include <hip/hip_runtime.h>
#include <hip/hip_bf16.h>

#define S_LEN 1024
#define DH 64
#define QB 64      // q rows per workgroup
#define KT 64      // k rows per tile
#define NKT 16     // S_LEN / KT
#define LDP 72     // padded LDS row length (bf16 elems); 144B stride

typedef __attribute__((ext_vector_type(8))) short bf16x8;
typedef __attribute__((ext_vector_type(4))) float f32x4;
typedef unsigned long long u64;

__device__ __forceinline__ unsigned short f2bf(float f) {
  unsigned u = __float_as_uint(f);
  u = u + 0x7FFFu + ((u >> 16) & 1u);   // RNE
  return (unsigned short)(u >> 16);
}
__device__ __forceinline__ float bf2f(unsigned short s) {
  return __uint_as_float((unsigned)s << 16);
}
__device__ __forceinline__ unsigned pk2(float a, float b) {
  __hip_bfloat162 h = __float22bfloat162_rn(float2{a, b});
  return *reinterpret_cast<unsigned*>(&h);
}

// ---- pre-pass: pack int32 mask -> 1 bit/elem ----
__global__ __launch_bounds__(256)
void maskpack_kernel(const int* __restrict__ mask, u64* __restrict__ bits) {
  int w    = blockIdx.x * 4 + (threadIdx.x >> 6);
  int lane = threadIdx.x & 63;
  int m = mask[(size_t)w * 64 + lane];
  u64 word = __ballot(m != 0);
  if (lane == 0) bits[w] = word;
}

__global__ __launch_bounds__(256, 3)
void sdpa_kernel(const float* __restrict__ qg, const float* __restrict__ kg,
                 const float* __restrict__ vg, const u64* __restrict__ bitsg,
                 float* __restrict__ outg, float* __restrict__ attng)
{
  // LDS 46 KB -> 3 blocks/CU (round 26: occupancy in this range not limiting).
  // Double-buffered K/V in pass 2 -> 1 barrier/tile. Qs aliases Ps.
  __shared__ unsigned short QsPs[QB][LDP];
  __shared__ unsigned short Ksb[2][KT][LDP];
  __shared__ unsigned short Vtb[2][DH][LDP];
  __shared__ float invLds[QB];

  unsigned short (*Qs)[LDP] = QsPs;
  unsigned short (*Ps)[16][LDP] = (unsigned short (*)[16][LDP])QsPs;

  const int tid  = threadIdx.x;
  const int wid  = tid >> 6;
  const int lane = tid & 63;
  const int lrow = lane & 15;
  const int lhi  = lane >> 4;

  // XCD swizzle (validated round 21)
  const int P = blockIdx.x;
  const int L = (P & 7) * 128 + (P >> 3);     // bijective: 1024 % 8 == 0
  const int qbi = L & 15;
  const int bh  = L >> 4;
  const int b   = bh >> 4;

  const size_t qkv_off = (size_t)bh * (S_LEN * DH);
  const float* qb_ptr = qg + qkv_off + (size_t)qbi * QB * DH;
  const float* kb_ptr = kg + qkv_off;
  const float* vb_ptr = vg + qkv_off;
  const int q0 = qbi * QB;
  const int qrow_l = wid * 16 + lhi * 4;

  const u64* bptr = bitsg + ((size_t)(b * S_LEN + q0 + qrow_l)) * NKT;  // + r*NKT + kt
  float* attn_base = attng + (size_t)bh * (S_LEN * S_LEN);

  // ---- prologue: issue tile-0 K + bits loads ----
  float4 Kp[4];
  u64 Bc[4], Bn[4];
  #pragma unroll
  for (int i = 0; i < 4; ++i) {
    int idx = tid + 256 * i;
    Kp[i] = *(const float4*)(kb_ptr + (size_t)(idx >> 4) * DH + ((idx & 15) << 2));
  }
  #pragma unroll
  for (int r = 0; r < 4; ++r) Bc[r] = bptr[r * NKT + 0];

  // ---- stage Q (f32 -> bf16) ----
  #pragma unroll
  for (int i = 0; i < 4; ++i) {
    int idx = tid + 256 * i;
    int row = idx >> 4, c4 = (idx & 15) << 2;
    float4 t = *(const float4*)(qb_ptr + row * DH + c4);
    uint2 w; w.x = pk2(t.x, t.y); w.y = pk2(t.z, t.w);
    *(uint2*)&Qs[row][c4] = w;
  }
  __syncthreads();
  const bf16x8 qf0 = *(const bf16x8*)&Qs[wid * 16 + lrow][lhi * 8];
  const bf16x8 qf1 = *(const bf16x8*)&Qs[wid * 16 + lrow][32 + lhi * 8];

  // stage K tile 0 into Ksb[0]; issue tile-1 loads
  #pragma unroll
  for (int i = 0; i < 4; ++i) {
    int idx = tid + 256 * i;
    int row = idx >> 4, c4 = (idx & 15) << 2;
    float4 t = Kp[i];
    uint2 w; w.x = pk2(t.x, t.y); w.y = pk2(t.z, t.w);
    *(uint2*)&Ksb[0][row][c4] = w;
  }
  #pragma unroll
  for (int i = 0; i < 4; ++i) {
    int idx = tid + 256 * i;
    Kp[i] = *(const float4*)(kb_ptr + (size_t)KT * DH + (size_t)(idx >> 4) * DH + ((idx & 15) << 2));
  }

  // ================= pass 1: rowsums, K ping-pong over Ksb[0/1], 1 barrier/tile =====
  float rs[4] = {0.f, 0.f, 0.f, 0.f};

  for (int kt = 0; kt < NKT; ++kt) {
    __syncthreads();   // tile kt staged & visible; reads of the other buffer done

    unsigned short (*cur)[LDP] = Ksb[kt & 1];
    unsigned short (*nxt)[LDP] = Ksb[(kt & 1) ^ 1];

    if (kt + 1 < NKT) {
      #pragma unroll
      for (int i = 0; i < 4; ++i) {
        int idx = tid + 256 * i;
        int row = idx >> 4, c4 = (idx & 15) << 2;
        float4 t = Kp[i];
        uint2 w; w.x = pk2(t.x, t.y); w.y = pk2(t.z, t.w);
        *(uint2*)&nxt[row][c4] = w;
      }
      if (kt + 2 < NKT) {
        const float* kn = kb_ptr + (size_t)(kt + 2) * KT * DH;
        #pragma unroll
        for (int i = 0; i < 4; ++i) {
          int idx = tid + 256 * i;
          Kp[i] = *(const float4*)(kn + (size_t)(idx >> 4) * DH + ((idx & 15) << 2));
        }
      }
      #pragma unroll
      for (int r = 0; r < 4; ++r) Bn[r] = bptr[r * NKT + kt + 1];   // bits: kt+1 (NOT kt+2)
    }

    #pragma unroll
    for (int nt = 0; nt < 4; ++nt) {
      bf16x8 kf0 = *(const bf16x8*)&cur[nt * 16 + lrow][lhi * 8];
      bf16x8 kf1 = *(const bf16x8*)&cur[nt * 16 + lrow][32 + lhi * 8];
      f32x4 acc = {0.f, 0.f, 0.f, 0.f};
      acc = __builtin_amdgcn_mfma_f32_16x16x32_bf16(qf0, kf0, acc, 0, 0, 0);
      acc = __builtin_amdgcn_mfma_f32_16x16x32_bf16(qf1, kf1, acc, 0, 0, 0);
      #pragma unroll
      for (int r = 0; r < 4; ++r) {
        bool ok = ((Bc[r] >> (nt * 16 + lrow)) & 1ull) != 0;
        float p = ok ? __expf(acc[r] * 0.125f) : 0.f;
        rs[r] += p;
      }
    }
    if (kt + 1 < NKT) {
      #pragma unroll
      for (int r = 0; r < 4; ++r) Bc[r] = Bn[r];
    }
  }

  // ---- rowsum reduce across the 16 lanes sharing each q-row ----
  #pragma unroll
  for (int r = 0; r < 4; ++r) {
    float v = rs[r];
    v += __shfl_xor(v, 1);
    v += __shfl_xor(v, 2);
    v += __shfl_xor(v, 4);
    v += __shfl_xor(v, 8);
    rs[r] = v;
  }
  float inv[4];
  #pragma unroll
  for (int r = 0; r < 4; ++r) inv[r] = 1.0f / rs[r];
  if (lrow == 0) {
    #pragma unroll
    for (int r = 0; r < 4; ++r) invLds[qrow_l + r] = inv[r];
  }

  // ---- prefetch pass-2 tile 0 (K, V, bits); latency hides under the reduce ----
  float4 Vp[4];
  #pragma unroll
  for (int i = 0; i < 4; ++i) {
    int idx = tid + 256 * i;
    Kp[i] = *(const float4*)(kb_ptr + (size_t)(idx >> 4) * DH + ((idx & 15) << 2));
    Vp[i] = *(const float4*)(vb_ptr + (size_t)(idx & 63) * DH + ((idx >> 6) << 2));
  }
  #pragma unroll
  for (int r = 0; r < 4; ++r) Bc[r] = bptr[r * NKT + 0];

  f32x4 oacc[4];
  #pragma unroll
  for (int dt = 0; dt < 4; ++dt) oacc[dt] = (f32x4){0.f, 0.f, 0.f, 0.f};

  // stage pass-2 tile 0 into pair 0 (after a barrier: pass-1 reads done)
  __syncthreads();
  #pragma unroll
  for (int i = 0; i < 4; ++i) {
    int idx = tid + 256 * i;
    int row = idx >> 4, c4 = (idx & 15) << 2;
    float4 t = Kp[i];
    uint2 w; w.x = pk2(t.x, t.y); w.y = pk2(t.z, t.w);
    *(uint2*)&Ksb[0][row][c4] = w;
  }
  #pragma unroll
  for (int i = 0; i < 4; ++i) {
    int idx = tid + 256 * i;
    int row = idx & 63, c4 = (idx >> 6) << 2;
    float4 t = Vp[i];
    Vtb[0][c4 + 0][row] = f2bf(t.x);
    Vtb[0][c4 + 1][row] = f2bf(t.y);
    Vtb[0][c4 + 2][row] = f2bf(t.z);
    Vtb[0][c4 + 3][row] = f2bf(t.w);
  }
  // issue tile-1 loads
  #pragma unroll
  for (int i = 0; i < 4; ++i) {
    int idx = tid + 256 * i;
    Kp[i] = *(const float4*)(kb_ptr + (size_t)KT * DH + (size_t)(idx >> 4) * DH + ((idx & 15) << 2));
    Vp[i] = *(const float4*)(vb_ptr + (size_t)KT * DH + (size_t)(idx & 63) * DH + ((idx >> 6) << 2));
  }

  // ================= pass 2: double-buffered, 1 barrier/tile =================
  for (int kt = 0; kt < NKT; ++kt) {
    __syncthreads();   // tile kt's buffers staged & visible; reads of other pair done
                       // (kt=0: also publishes invLds)

    const int cb = kt & 1;
    unsigned short (*Kc)[LDP] = Ksb[cb];
    unsigned short (*Vc)[LDP] = Vtb[cb];

    if (kt + 1 < NKT) {
      // stage tile kt+1 into the idle pair (no reader this iteration)
      unsigned short (*Kn)[LDP] = Ksb[cb ^ 1];
      unsigned short (*Vn)[LDP] = Vtb[cb ^ 1];
      #pragma unroll
      for (int i = 0; i < 4; ++i) {
        int idx = tid + 256 * i;
        int row = idx >> 4, c4 = (idx & 15) << 2;
        float4 t = Kp[i];
        uint2 w; w.x = pk2(t.x, t.y); w.y = pk2(t.z, t.w);
        *(uint2*)&Kn[row][c4] = w;
      }
      #pragma unroll
      for (int i = 0; i < 4; ++i) {
        int idx = tid + 256 * i;
        int row = idx & 63, c4 = (idx >> 6) << 2;
        float4 t = Vp[i];
        Vn[c4 + 0][row] = f2bf(t.x);
        Vn[c4 + 1][row] = f2bf(t.y);
        Vn[c4 + 2][row] = f2bf(t.z);
        Vn[c4 + 3][row] = f2bf(t.w);
      }
      if (kt + 2 < NKT) {
        const float* kn = kb_ptr + (size_t)(kt + 2) * KT * DH;
        const float* vn = vb_ptr + (size_t)(kt + 2) * KT * DH;
        #pragma unroll
        for (int i = 0; i < 4; ++i) {
          int idx = tid + 256 * i;
          Kp[i] = *(const float4*)(kn + (size_t)(idx >> 4) * DH + ((idx & 15) << 2));
          Vp[i] = *(const float4*)(vn + (size_t)(idx & 63) * DH + ((idx >> 6) << 2));
        }
      }
      // bits pipeline is ONE tile deep: kt+1 (round-27 bug was kt+2 here)
      #pragma unroll
      for (int r = 0; r < 4; ++r) Bn[r] = bptr[r * NKT + kt + 1];
    }

    // QK^T + masked exp -> per-wave bf16 P tile (uses Bc = tile kt's bits)
    #pragma unroll
    for (int nt = 0; nt < 4; ++nt) {
      bf16x8 kf0 = *(const bf16x8*)&Kc[nt * 16 + lrow][lhi * 8];
      bf16x8 kf1 = *(const bf16x8*)&Kc[nt * 16 + lrow][32 + lhi * 8];
      f32x4 acc = {0.f, 0.f, 0.f, 0.f};
      acc = __builtin_amdgcn_mfma_f32_16x16x32_bf16(qf0, kf0, acc, 0, 0, 0);
      acc = __builtin_amdgcn_mfma_f32_16x16x32_bf16(qf1, kf1, acc, 0, 0, 0);
      #pragma unroll
      for (int r = 0; r < 4; ++r) {
        bool ok = ((Bc[r] >> (nt * 16 + lrow)) & 1ull) != 0;
        float p = ok ? __expf(acc[r] * 0.125f) : 0.f;
        Ps[wid][lhi * 4 + r][nt * 16 + lrow] = f2bf(p);
      }
    }

    // pin compiler ordering: all Ps writes issue before cross-lane fragment reads
    asm volatile("" ::: "memory");

    // PV (per-wave Ps: in-order DS pipe; Vc protected by the dbuf barrier scheme)
    bf16x8 pf0 = *(const bf16x8*)&Ps[wid][lrow][lhi * 8];
    bf16x8 pf1 = *(const bf16x8*)&Ps[wid][lrow][32 + lhi * 8];
    #pragma unroll
    for (int dt = 0; dt < 4; ++dt) {
      bf16x8 vf0 = *(const bf16x8*)&Vc[dt * 16 + lrow][lhi * 8];
      bf16x8 vf1 = *(const bf16x8*)&Vc[dt * 16 + lrow][32 + lhi * 8];
      oacc[dt] = __builtin_amdgcn_mfma_f32_16x16x32_bf16(pf0, vf0, oacc[dt], 0, 0, 0);
      oacc[dt] = __builtin_amdgcn_mfma_f32_16x16x32_bf16(pf1, vf1, oacc[dt], 0, 0, 0);
    }

    // normalized attn store: NON-TEMPORAL f32x4 rows (4 rows x 256B per j-step)
    {
      float* ab = attn_base + (size_t)(q0 + wid * 16) * S_LEN + kt * KT;
      #pragma unroll
      for (int j = 0; j < 4; ++j) {
        int flat = lane + 64 * j;
        int rowl = flat >> 4;
        int c4   = (flat & 15) << 2;
        float iv = invLds[wid * 16 + rowl];
        const unsigned short* pr = &Ps[wid][rowl][c4];
        f32x4 st;
        st[0] = bf2f(pr[0]) * iv;
        st[1] = bf2f(pr[1]) * iv;
        st[2] = bf2f(pr[2]) * iv;
        st[3] = bf2f(pr[3]) * iv;
        __builtin_nontemporal_store(st, (f32x4*)(ab + (size_t)rowl * S_LEN + c4));
      }
    }

    if (kt + 1 < NKT) {
      #pragma unroll
      for (int r = 0; r < 4; ++r) Bc[r] = Bn[r];
    }
  }

  // ---- out epilogue (non-temporal: write-once stream) ----
  #pragma unroll
  for (int dt = 0; dt < 4; ++dt)
    #pragma unroll
    for (int r = 0; r < 4; ++r)
      __builtin_nontemporal_store(oacc[dt][r] * inv[r],
          outg + qkv_off + (size_t)(q0 + qrow_l + r) * DH + dt * 16 + lrow);
}

extern "C" void kernel_launch(void* const* d_in, const int* in_sizes, int n_in,
                              void* d_out, int out_size, void* d_ws, size_t ws_size,
                              hipStream_t stream) {
  const float* q    = (const float*)d_in[0];
  const float* k    = (const float*)d_in[1];
  const float* v    = (const float*)d_in[2];
  const int*   mask = (const int*)d_in[3];
  float* out  = (float*)d_out;
  float* attn = out + (size_t)4 * 16 * 1024 * 64;

  const size_t nwords = (size_t)4 * S_LEN * NKT;    // 65536 u64 = 512 KB
  u64* bits = (u64*)d_ws;                            // ws_size >= 512 KB (verified)
  maskpack_kernel<<<dim3(nwords / 4), dim3(256), 0, stream>>>(mask, bits);
  sdpa_kernel<<<dim3(64 * 16), dim3(256), 0, stream>>>(q, k, v, bits, out, attn);
}